// Round 1
// 108.079 us; speedup vs baseline: 1.0000x; 1.0000x over previous
//
#include <hip/hip_runtime.h>

// ConvQuadInterp3d: 3x3x3 replicate-padded stencil, quadratic peak refinement.
// Input  x: FP32, (2,1,10,512,512)
// Output: FP32, coords_max (2,1,3,10,512,512) ++ y_max (2,1,10,512,512)
// Coords channel order: ch0=d+dx2, ch1=h+dx1, ch2=w+dx0.
//
// R16: w-VECTORIZED 4-wide on top of R15's h-pairing. One thread owns a
// 4(w) x 2(h) output tile. Per (z,row) segment: 1 aligned float4 + 2 halo
// scalars (6 values spanning w0-1..w0+4). Loads/output 18->4.5, stores
// 4 scalar -> 1 float4 per plane, 26-neighbor max via shared separable
// column-max3 (v_max3) with exact center exclusion. Rationale: R14 showed
// instruction ISSUE is binding, not L1 service -- this cuts VMEM issue 4x
// and total issue ~2x while keeping R13/R15's coalescing (wave spans
// 1024B contiguous per load/store instr).
//
// NaN discipline: fast-math-safe by construction -- keep = |num| <= 0.7*|det|
// evaluated WITHOUT dividing; 1/det only taken when keep (=> det != 0).

constexpr int Dd = 10, Hh = 512, Ww = 512;
constexpr int HW  = Hh * Ww;        // 262144
constexpr int DHW = Dd * HW;        // 2621440
constexpr float BONUS_F = 10.0f;

__global__ __launch_bounds__(256) void quad_kernel(
        const float* __restrict__ x, float* __restrict__ out) {
    const int tx = threadIdx.x;                        // lane 0..63
    const int w0 = (blockIdx.x << 8) + (tx << 2);      // 0..508, step 4
    const int h0 = (blockIdx.y << 3) + (threadIdx.y << 1);  // even row of pair
    const int bd = blockIdx.z;                         // 0..19: b*Dd + d
    const int d  = bd % Dd;
    const int b  = bd / Dd;

    // replicate-clamped indices
    const int wl = (w0 == 0) ? 0 : w0 - 1;
    const int wr = (w0 + 4 > Ww - 1) ? Ww - 1 : w0 + 4;
    const int zm = (d == 0) ? bd : bd - 1, zp = (d == Dd - 1) ? bd : bd + 1;
    const int hr[4] = { (h0 == 0) ? 0 : h0 - 1, h0, h0 + 1,
                        (h0 + 2 > Hh - 1) ? Hh - 1 : h0 + 2 };
    const int zz[3] = { zm, bd, zp };

    // V[z][r][k]: value at (plane z, row r, w0-1+k), k=0..5.
    // 12 segments x (1 dwordx4 + 2 dword) = 36 load instrs for 8 outputs.
    float V[3][4][6];
#pragma unroll
    for (int z = 0; z < 3; ++z) {
        const float* pl = x + (size_t)zz[z] * HW;
#pragma unroll
        for (int r = 0; r < 4; ++r) {
            const float* rp = pl + (size_t)hr[r] * Ww;
            const float4 v4 = *reinterpret_cast<const float4*>(rp + w0);
            V[z][r][0] = rp[wl];
            V[z][r][1] = v4.x;  V[z][r][2] = v4.y;
            V[z][r][3] = v4.z;  V[z][r][4] = v4.w;
            V[z][r][5] = rp[wr];
        }
    }

    // Separable neighbor-max precompute, shared across the 4x2 tile.
    // zc[r][j]  = max over z(0..2), cols(j..j+2) of row r  (full 3x3 slab)
    // pm2[r-1][j] (r=1,2) = same slab EXCLUDING the (z=1, col=j+1) center.
    // fmaxf(fmaxf(a,b),c) fuses to v_max3_f32.
    float zc[4][4], pm2[2][4];
#pragma unroll
    for (int r = 0; r < 4; ++r)
#pragma unroll
        for (int j = 0; j < 4; ++j) {
            const float c0 = fmaxf(fmaxf(V[0][r][j], V[0][r][j+1]), V[0][r][j+2]);
            const float c1 = fmaxf(fmaxf(V[1][r][j], V[1][r][j+1]), V[1][r][j+2]);
            const float c2 = fmaxf(fmaxf(V[2][r][j], V[2][r][j+1]), V[2][r][j+2]);
            zc[r][j] = fmaxf(fmaxf(c0, c1), c2);
            if (r == 1 || r == 2) {
                const float lr = fmaxf(V[1][r][j], V[1][r][j+2]);   // z=1 row sans center
                pm2[r-1][j] = fmaxf(fmaxf(c0, c2), lr);
            }
        }

#pragma unroll
    for (int o = 0; o < 2; ++o) {
        const int r0 = o, r1 = o + 1, r2 = o + 2;
        float rd[4], rh[4], rw[4], ry[4];           // compile-time indexed only

#pragma unroll
        for (int j = 0; j < 4; ++j) {
            const float xc = V[1][r1][j+1];

            // 26-neighbor max: full slabs of rows r0,r2 + center-excluded slab
            // of row r1, then clamp at 0. Exact exclusion of ONLY the center.
            const float nm = fmaxf(
                fmaxf(fmaxf(zc[r0][j], zc[r2][j]), pm2[r1-1][j]), 0.0f);
            const bool m = xc > nm;

            const float gx  = 0.5f * (V[1][r1][j+2] - V[1][r1][j]);
            const float gy  = 0.5f * (V[1][r2][j+1] - V[1][r0][j+1]);
            const float gs  = 0.5f * (V[2][r1][j+1] - V[0][r1][j+1]);
            const float dxx = V[1][r1][j]   + V[1][r1][j+2] - 2.0f * xc;
            const float dyy = V[1][r0][j+1] + V[1][r2][j+1] - 2.0f * xc;
            const float dss = V[0][r1][j+1] + V[2][r1][j+1] - 2.0f * xc;
            const float dxy = 0.25f * (V[1][r0][j]   + V[1][r2][j+2]
                                     - V[1][r2][j]   - V[1][r0][j+2]);
            const float dys = 0.25f * (V[0][r0][j+1] + V[2][r2][j+1]
                                     - V[2][r0][j+1] - V[0][r2][j+1]);
            const float dxs = 0.25f * (V[0][r1][j]   + V[2][r1][j+2]
                                     - V[2][r1][j]   - V[0][r1][j+2]);

            // Cramer numerators of H*s = g. Rm eps (<=1e-7) dropped: near-
            // singular dets rejected by keep, like ref's far>0.7 clamp.
            const float c00 = dyy * dss - dys * dys;
            const float c01 = dxy * dss - dys * dxs;
            const float c02 = dxy * dys - dyy * dxs;
            const float det = dxx * c00 - dxy * c01 + dxs * c02;
            const float t1  = gy * dss - dys * gs;
            const float t2  = gy * dys - dyy * gs;
            const float t3  = dxy * gs - gy * dxs;
            const float nx  = gx * c00 - dxy * t1 + dxs * t2;    // sx * det
            const float ny  = dxx * t1 - gx * c01 + dxs * t3;    // sy * det
            const float ns  = dxx * (-t2) - dxy * t3 + gx * c02; // ss * det

            // keep <=> m && det!=0 && all |num/det| <= 0.7, WITHOUT dividing.
            const float lim = 0.7f * fabsf(det);
            const bool keep = m && (fabsf(det) > 0.0f) &&
                              (fabsf(nx) <= lim) && (fabsf(ny) <= lim) &&
                              (fabsf(ns) <= lim);
            const float rdet = keep ? (1.0f / det) : 0.0f;
            const float dx0 = -nx * rdet;            // keep ? -nx/det : 0
            const float dx1 = -ny * rdet;
            const float dx2 = -ns * rdet;

            const float dy_ = 0.5f * (gx * dx0 + gy * dx1 + gs * dx2);

            rd[j] = (float)d + dx2;
            rh[j] = (float)(h0 + o) + dx1;
            rw[j] = (float)(w0 + j) + dx0;
            ry[j] = xc + dy_ + (m ? BONUS_F : 0.0f);
        }

        // 4 float4 stores per output row (vs 16 scalar): wave spans 1024B.
        const size_t idx = (size_t)d * HW + (size_t)(h0 + o) * Ww + w0;
        *reinterpret_cast<float4*>(out + ((size_t)(b * 3 + 0)) * DHW + idx) =
            make_float4(rd[0], rd[1], rd[2], rd[3]);
        *reinterpret_cast<float4*>(out + ((size_t)(b * 3 + 1)) * DHW + idx) =
            make_float4(rh[0], rh[1], rh[2], rh[3]);
        *reinterpret_cast<float4*>(out + ((size_t)(b * 3 + 2)) * DHW + idx) =
            make_float4(rw[0], rw[1], rw[2], rw[3]);
        *reinterpret_cast<float4*>(out + (size_t)6 * DHW + (size_t)b * DHW + idx) =
            make_float4(ry[0], ry[1], ry[2], ry[3]);
    }
}

extern "C" void kernel_launch(void* const* d_in, const int* in_sizes, int n_in,
                              void* d_out, int out_size, void* d_ws, size_t ws_size,
                              hipStream_t stream) {
    (void)in_sizes; (void)n_in; (void)out_size; (void)d_ws; (void)ws_size;
    const float* x = (const float*)d_in[0];
    float* out = (float*)d_out;
    dim3 block(64, 4, 1);
    dim3 grid(Ww / 256, Hh / 8, 2 * Dd);   // (2, 64, 20) = 2560 blocks
    quad_kernel<<<grid, block, 0, stream>>>(x, out);
}